// Round 1
// baseline (500.140 us; speedup 1.0000x reference)
//
#include <hip/hip_runtime.h>
#include <hip/hip_bf16.h>

typedef __bf16 bf16_t;
typedef __bf16 bf16x8 __attribute__((ext_vector_type(8)));
typedef float f32x4 __attribute__((ext_vector_type(4)));

#define T_TOK 4096
#define H_DIM 7168
#define QLORA 1536
#define KVLORA 512
#define ROPE_D 64
#define NOPE_D 128
#define NHEAD 16
#define NQKV 2112   /* QLORA + KVLORA + ROPE */
#define NQB  3072   /* NHEAD * 192 */
#define EPS_F 1e-6f

// ---------------- elementwise helpers ----------------

__global__ void cast_f32_bf16(const float* __restrict__ in, bf16_t* __restrict__ out, long n8)
{
    long stride = (long)gridDim.x * blockDim.x;
    for (long i = (long)blockIdx.x * blockDim.x + threadIdx.x; i < n8; i += stride) {
        const float4 a = ((const float4*)in)[i * 2];
        const float4 b = ((const float4*)in)[i * 2 + 1];
        bf16x8 v;
        v[0] = (bf16_t)a.x; v[1] = (bf16_t)a.y; v[2] = (bf16_t)a.z; v[3] = (bf16_t)a.w;
        v[4] = (bf16_t)b.x; v[5] = (bf16_t)b.y; v[6] = (bf16_t)b.z; v[7] = (bf16_t)b.w;
        ((bf16x8*)out)[i] = v;
    }
}

// out[C][R] (bf16) = transpose of in[R][C] (f32)
__global__ __launch_bounds__(256) void transpose_cast(const float* __restrict__ in,
                                                      bf16_t* __restrict__ out, int R, int C)
{
    __shared__ float tile[32][33];
    const int bx = blockIdx.x * 32;   // col block of in
    const int by = blockIdx.y * 32;   // row block of in
    const int tx = threadIdx.x & 31, ty = threadIdx.x >> 5;
    #pragma unroll
    for (int r = ty; r < 32; r += 8)
        tile[r][tx] = in[(long)(by + r) * C + bx + tx];
    __syncthreads();
    #pragma unroll
    for (int r = ty; r < 32; r += 8)
        out[(long)(bx + r) * R + by + tx] = (bf16_t)tile[tx][r];
}

__device__ inline float block_sum_256(float v)
{
    #pragma unroll
    for (int off = 32; off > 0; off >>= 1) v += __shfl_xor(v, off, 64);
    __shared__ float tmp[4];
    if ((threadIdx.x & 63) == 0) tmp[threadIdx.x >> 6] = v;
    __syncthreads();
    return tmp[0] + tmp[1] + tmp[2] + tmp[3];
}

// RMS-norm qkv[:, :1536] -> bf16 q_a
__global__ __launch_bounds__(256) void rms_q_kernel(const float* __restrict__ qkv,
                                                    const float* __restrict__ w,
                                                    bf16_t* __restrict__ q_a)
{
    const int t = blockIdx.x;
    const float* x = qkv + (long)t * NQKV;
    float loc[6];
    float ss = 0.f;
    #pragma unroll
    for (int i = 0; i < 6; i++) {
        float v = x[threadIdx.x + 256 * i];
        loc[i] = v; ss += v * v;
    }
    ss = block_sum_256(ss);
    const float sc = rsqrtf(ss / (float)QLORA + EPS_F);
    #pragma unroll
    for (int i = 0; i < 6; i++) {
        int idx = threadIdx.x + 256 * i;
        q_a[(long)t * QLORA + idx] = (bf16_t)(loc[i] * sc * w[idx]);
    }
}

// k-side: RMS-norm latent[:512] + rope latent[512:576]; write k_out, k_cache, rope_cache
__global__ __launch_bounds__(256) void k_side_kernel(const float* __restrict__ qkv,
                                                     const float* __restrict__ w_kv,
                                                     const float* __restrict__ cos_sin,
                                                     const int* __restrict__ positions,
                                                     const int* __restrict__ slot_map,
                                                     float* __restrict__ k_out,
                                                     float* __restrict__ kc_out,
                                                     float* __restrict__ rc_out)
{
    const int t = blockIdx.x;
    const float* lat = qkv + (long)t * NQKV + QLORA;
    const float v0 = lat[threadIdx.x];
    const float v1 = lat[threadIdx.x + 256];
    float ss = v0 * v0 + v1 * v1;
    ss = block_sum_256(ss);
    const float sc = rsqrtf(ss / (float)KVLORA + EPS_F);
    const int slot = slot_map[t];
    const float a0 = v0 * sc * w_kv[threadIdx.x];
    const float a1 = v1 * sc * w_kv[threadIdx.x + 256];
    k_out[(long)t * 576 + threadIdx.x]        = a0;
    k_out[(long)t * 576 + 256 + threadIdx.x]  = a1;
    kc_out[(long)slot * KVLORA + threadIdx.x]       = a0;
    kc_out[(long)slot * KVLORA + 256 + threadIdx.x] = a1;
    if (threadIdx.x < 32) {
        const int j = threadIdx.x;
        const int pos = positions[t];
        const float c = cos_sin[pos * 64 + j];
        const float s = cos_sin[pos * 64 + 32 + j];
        const float x1 = lat[KVLORA + 2 * j];
        const float x2 = lat[KVLORA + 2 * j + 1];
        const float o1 = x1 * c - x2 * s;
        const float o2 = x2 * c + x1 * s;
        k_out[(long)t * 576 + 512 + j]      = o1;
        k_out[(long)t * 576 + 512 + 32 + j] = o2;
        rc_out[(long)slot * 64 + j]      = o1;
        rc_out[(long)slot * 64 + 32 + j] = o2;
    }
}

// split q_b into q_nope (bf16, [h][t][128]) and roped q_pe -> q_out[..., 512:576]
__global__ __launch_bounds__(256) void split_q_kernel(const float* __restrict__ q_b,
                                                      const float* __restrict__ cos_sin,
                                                      const int* __restrict__ positions,
                                                      bf16_t* __restrict__ q_nope,
                                                      float* __restrict__ q_out)
{
    const int t = blockIdx.x;
    const float* row = q_b + (long)t * NQB;
    #pragma unroll
    for (int i = 0; i < 8; i++) {
        int idx = threadIdx.x + 256 * i;      // 0..2047
        int h = idx >> 7, n = idx & 127;
        q_nope[((long)h * T_TOK + t) * NOPE_D + n] = (bf16_t)row[h * 192 + n];
    }
    const int pos = positions[t];
    #pragma unroll
    for (int i = 0; i < 2; i++) {
        int p = threadIdx.x + 256 * i;        // 0..511
        int h = p >> 5, j = p & 31;
        const float c = cos_sin[pos * 64 + j];
        const float s = cos_sin[pos * 64 + 32 + j];
        const float x1 = row[h * 192 + 128 + 2 * j];
        const float x2 = row[h * 192 + 128 + 2 * j + 1];
        q_out[(long)t * 9216 + h * 576 + 512 + j]      = x1 * c - x2 * s;
        q_out[(long)t * 9216 + h * 576 + 512 + 32 + j] = x2 * c + x1 * s;
    }
}

// ---------------- bf16 MFMA GEMM: C(MxN f32) = A(MxK) * B^T(NxK) ----------------
#define BM 128
#define BN 64
#define BKT 64
#define LDST (BKT + 8)   /* padded LDS stride (bf16 elems); 144B rows, 16B aligned */

__global__ __launch_bounds__(256) void gemm_bf16(
    const bf16_t* __restrict__ A, int lda, long sA,
    const bf16_t* __restrict__ Bt, int ldb, long sB,
    float* __restrict__ C, int ldc, long sC,
    int K)
{
    __shared__ bf16_t As[BM * LDST];
    __shared__ bf16_t Bs[BN * LDST];
    const int tid = threadIdx.x;
    const int bz = blockIdx.z;
    const bf16_t* Ab = A + bz * sA + (long)(blockIdx.y * BM) * lda;
    const bf16_t* Bb = Bt + bz * sB + (long)(blockIdx.x * BN) * ldb;
    float* Cb = C + bz * sC + (long)(blockIdx.y * BM) * ldc + blockIdx.x * BN;

    const int lane = tid & 63;
    const int w = tid >> 6;          // 0..3 -> 2x2 wave grid
    const int wr = w >> 1, wc = w & 1;
    const int fr = lane & 15;        // fragment row
    const int kg = lane >> 4;        // k-group (0..3)

    const int arow = tid >> 3;       // 0..31
    const int acol = (tid & 7) * 8;  // 0..56

    f32x4 acc[4][2] = {};

    for (int k0 = 0; k0 < K; k0 += BKT) {
        __syncthreads();
        #pragma unroll
        for (int rr = 0; rr < BM; rr += 32) {
            bf16x8 v = *(const bf16x8*)(Ab + (long)(arow + rr) * lda + k0 + acol);
            *(bf16x8*)(&As[(arow + rr) * LDST + acol]) = v;
        }
        #pragma unroll
        for (int rr = 0; rr < BN; rr += 32) {
            bf16x8 v = *(const bf16x8*)(Bb + (long)(arow + rr) * ldb + k0 + acol);
            *(bf16x8*)(&Bs[(arow + rr) * LDST + acol]) = v;
        }
        __syncthreads();
        #pragma unroll
        for (int ks = 0; ks < BKT; ks += 32) {
            bf16x8 af[4], bfr[2];
            #pragma unroll
            for (int i = 0; i < 4; i++)
                af[i] = *(const bf16x8*)(&As[(wr * 64 + i * 16 + fr) * LDST + ks + kg * 8]);
            #pragma unroll
            for (int j = 0; j < 2; j++)
                bfr[j] = *(const bf16x8*)(&Bs[(wc * 32 + j * 16 + fr) * LDST + ks + kg * 8]);
            #pragma unroll
            for (int i = 0; i < 4; i++)
                #pragma unroll
                for (int j = 0; j < 2; j++)
                    acc[i][j] = __builtin_amdgcn_mfma_f32_16x16x32_bf16(af[i], bfr[j], acc[i][j], 0, 0, 0);
        }
    }
    #pragma unroll
    for (int i = 0; i < 4; i++) {
        #pragma unroll
        for (int j = 0; j < 2; j++) {
            const int row0 = wr * 64 + i * 16 + kg * 4;
            const int col  = wc * 32 + j * 16 + fr;
            #pragma unroll
            for (int r = 0; r < 4; r++)
                Cb[(long)(row0 + r) * ldc + col] = acc[i][j][r];
        }
    }
}

// ---------------- launcher ----------------

extern "C" void kernel_launch(void* const* d_in, const int* in_sizes, int n_in,
                              void* d_out, int out_size, void* d_ws, size_t ws_size,
                              hipStream_t stream)
{
    const float* hs       = (const float*)d_in[0];
    const int*   positions= (const int*)d_in[1];
    const float* w_qkv_a  = (const float*)d_in[2];
    const float* q_a_ln_w = (const float*)d_in[3];
    const float* w_q_b    = (const float*)d_in[4];
    const float* kv_a_ln_w= (const float*)d_in[5];
    const float* w_kc     = (const float*)d_in[6];
    const float* cos_sin  = (const float*)d_in[7];
    const float* k_cache_in  = (const float*)d_in[8];
    const float* rope_cache_in = (const float*)d_in[9];
    const int*   slot_map = (const int*)d_in[10];

    float* out   = (float*)d_out;
    float* q_out = out;                       // 4096*16*576
    float* k_out = out + 37748736;            // 4096*576
    float* kc_out = out + 40108032;           // 16384*512
    float* rc_out = out + 48496640;           // 16384*64

    char* ws = (char*)d_ws;
    bf16_t* hs_bf  = (bf16_t*)(ws + 0);            // 58,720,256 B
    float*  q_b    = (float*)(ws + 0);             // reuse after GEMM1 (50,331,648 B)
    bf16_t* wqkvaT = (bf16_t*)(ws + 58720256);     // 30,277,632 B
    bf16_t* wqbT   = (bf16_t*)(ws + 88997888);     //  9,437,184 B
    bf16_t* wkcT   = (bf16_t*)(ws + 98435072);     //  2,097,152 B
    float*  qkv    = (float*)(ws + 100532224);     // 34,603,008 B
    bf16_t* q_nope = (bf16_t*)(ws + 100532224);    // reuse after rms/k-side (16,777,216 B)
    bf16_t* q_a    = (bf16_t*)(ws + 135135232);    // 12,582,912 B -> total 147,718,144 B

    // caches: full copy, then scatter-overwrite in k_side_kernel
    hipMemcpyAsync(kc_out, k_cache_in, (size_t)16384 * 512 * 4, hipMemcpyDeviceToDevice, stream);
    hipMemcpyAsync(rc_out, rope_cache_in, (size_t)16384 * 64 * 4, hipMemcpyDeviceToDevice, stream);

    cast_f32_bf16<<<2048, 256, 0, stream>>>(hs, hs_bf, (long)T_TOK * H_DIM / 8);
    transpose_cast<<<dim3(NQKV / 32, H_DIM / 32), 256, 0, stream>>>(w_qkv_a, wqkvaT, H_DIM, NQKV);
    transpose_cast<<<dim3(NQB / 32, QLORA / 32), 256, 0, stream>>>(w_q_b, wqbT, QLORA, NQB);
    transpose_cast<<<dim3(512 / 32, 2048 / 32), 256, 0, stream>>>(w_kc, wkcT, 2048, 512);

    // GEMM1: qkv = hs @ w_qkv_a   (4096 x 2112, K=7168)
    gemm_bf16<<<dim3(NQKV / BN, T_TOK / BM, 1), 256, 0, stream>>>(
        hs_bf, H_DIM, 0, wqkvaT, H_DIM, 0, qkv, NQKV, 0, H_DIM);

    rms_q_kernel<<<T_TOK, 256, 0, stream>>>(qkv, q_a_ln_w, q_a);
    k_side_kernel<<<T_TOK, 256, 0, stream>>>(qkv, kv_a_ln_w, cos_sin, positions, slot_map,
                                             k_out, kc_out, rc_out);

    // GEMM2: q_b = q_a @ w_q_b   (4096 x 3072, K=1536)
    gemm_bf16<<<dim3(NQB / BN, T_TOK / BM, 1), 256, 0, stream>>>(
        q_a, QLORA, 0, wqbT, QLORA, 0, q_b, NQB, 0, QLORA);

    split_q_kernel<<<T_TOK, 256, 0, stream>>>(q_b, cos_sin, positions, q_nope, q_out);

    // GEMM3 (batched over heads): q_out[:, h, :512] = q_nope[h] @ w_kc[h]
    gemm_bf16<<<dim3(KVLORA / BN, T_TOK / BM, NHEAD), 256, 0, stream>>>(
        q_nope, NOPE_D, (long)T_TOK * NOPE_D,
        wkcT, 2048, 128,
        q_out, NHEAD * 576, 576, NOPE_D);
}